// Round 1
// 1531.302 us; speedup vs baseline: 1.1723x; 1.1723x over previous
//
#include <hip/hip_runtime.h>
#include <hip/hip_bf16.h>
#include <math.h>

#define B_    2
#define S_    2048
#define H_    4096
#define NH_   32
#define HD_   128
#define MTOK_ (B_ * S_)     // 4096 tokens
#define QKVN_ (3 * H_)      // 12288

using bf16_t = __hip_bfloat16;
typedef __bf16 bf16x8 __attribute__((ext_vector_type(8)));
typedef unsigned short u16x8 __attribute__((ext_vector_type(8)));
typedef float f32x4 __attribute__((ext_vector_type(4)));

// async global->LDS, 16B per lane; LDS base must be wave-uniform
// (HW writes lane i at base + i*16B).
#define ASYNC_COPY16(g, l)                                                     \
  __builtin_amdgcn_global_load_lds(                                            \
      (__attribute__((address_space(1))) void*)(g),                            \
      (__attribute__((address_space(3))) void*)(l), 16, 0, 0)

static __device__ __forceinline__ f32x4 mfma16x16(bf16x8 a, bf16x8 b, f32x4 c) {
  return __builtin_amdgcn_mfma_f32_16x16x32_bf16(a, b, c, 0, 0, 0);
}

static __device__ __forceinline__ float bits_to_f(unsigned short v) {
  union { unsigned int u; float f; } cv;
  cv.u = ((unsigned int)v) << 16;
  return cv.f;
}

// ---------------------------------------------------------------------------
// dtype probe: if the float inputs are fp32, random mantissa halves decode to
// huge bf16 values; if genuine bf16 (|x|<~0.2 here), all 64K u16s stay small.
// ---------------------------------------------------------------------------
__global__ void bh_detect(const unsigned short* __restrict__ p,
                          int* __restrict__ flag) {
  __shared__ float red[4];
  float m = 0.f;
  const int tid = threadIdx.x;
  for (int i = tid; i < 65536; i += 256) {
    const float f = fabsf(bits_to_f(p[i]));
    m = fmaxf(m, f);  // fmaxf(m, NaN) == m
  }
  for (int off = 1; off < 64; off <<= 1) m = fmaxf(m, __shfl_xor(m, off, 64));
  if ((tid & 63) == 0) red[tid >> 6] = m;
  __syncthreads();
  if (tid == 0) {
    const float mm = fmaxf(fmaxf(red[0], red[1]), fmaxf(red[2], red[3]));
    *flag = (mm > 1.0f) ? 1 : 0;  // 1 => inputs/outputs are fp32
  }
}

// ---------------------------------------------------------------------------
// one-shot dtype normalization: fp32 -> bf16 convert (or bf16 copy), so the
// GEMMs can always use the global_load_lds (async 16B) staging path.
// ---------------------------------------------------------------------------
__global__ __launch_bounds__(256)
void bh_convert(const void* __restrict__ src, bf16_t* __restrict__ dst,
                long n8, const int* __restrict__ flag) {
  const int isf = *flag;
  const long stride = (long)gridDim.x * 256;
  long i = (long)blockIdx.x * 256 + threadIdx.x;
  if (isf) {
    const f32x4* s = (const f32x4*)src;
    for (; i < n8; i += stride) {
      const f32x4 f0 = s[2 * i];
      const f32x4 f1 = s[2 * i + 1];
      bf16x8 o;
      o[0] = (__bf16)f0[0]; o[1] = (__bf16)f0[1];
      o[2] = (__bf16)f0[2]; o[3] = (__bf16)f0[3];
      o[4] = (__bf16)f1[0]; o[5] = (__bf16)f1[1];
      o[6] = (__bf16)f1[2]; o[7] = (__bf16)f1[3];
      *reinterpret_cast<bf16x8*>(dst + i * 8) = o;
    }
  } else {
    const u16x8* s = (const u16x8*)src;
    for (; i < n8; i += stride)
      reinterpret_cast<u16x8*>(dst)[i] = s[i];
  }
}

// fp32 staging: read 8 floats, convert, one ds_write_b128 (same LDS layout
// the async path produces).
static __device__ __forceinline__ void stage32(const float* __restrict__ g,
                                               bf16_t* __restrict__ l) {
  const f32x4 f0 = *reinterpret_cast<const f32x4*>(g);
  const f32x4 f1 = *reinterpret_cast<const f32x4*>(g + 4);
  bf16x8 o;
  o[0] = (__bf16)f0[0]; o[1] = (__bf16)f0[1];
  o[2] = (__bf16)f0[2]; o[3] = (__bf16)f0[3];
  o[4] = (__bf16)f1[0]; o[5] = (__bf16)f1[1];
  o[6] = (__bf16)f1[2]; o[7] = (__bf16)f1[3];
  *reinterpret_cast<bf16x8*>(l) = o;
}

// ---------------------------------------------------------------------------
// NT GEMM: C[m][n] = sum_k A[m][k]*Bw[n][k]. 128x128 tile, BK=32, 4 waves,
// 4x4 acc of 16x16x32 bf16 MFMA. AMODE/BMODE: 0 = operand always bf16,
// 1 = dtype per runtime flag. CMODE: 0 = store bf16, 1 = store per flag.
// ---------------------------------------------------------------------------
template <int AMODE, int BMODE, int CMODE>
__global__ __launch_bounds__(256, 2)
void bh_gemm(const void* __restrict__ Ap, int lda,
             const void* __restrict__ Bp, int ldb,
             void* __restrict__ Cp, int ldc, int N, int K,
             const int* __restrict__ flag) {
  __shared__ bf16_t As[128 * 32];
  __shared__ bf16_t Bs[128 * 32];
  const int isf = *flag;
  const bool a_f32 = AMODE && isf;
  const bool b_f32 = BMODE && isf;

  const int tid = threadIdx.x, wave = tid >> 6, lane = tid & 63;
  const int lq = lane >> 4, lc = lane & 15;
  const int m0 = blockIdx.y * 128, n0 = blockIdx.x * 128;
  const int wm = (wave >> 1) * 64, wn = (wave & 1) * 64;

  f32x4 acc[4][4] = {};

  const int srow  = wave * 16 + (lane >> 2);  // staging row (lane i -> i/4)
  const int skoff = (lane & 3) * 8;           // k-chunk of 8 elements

  const bf16_t* a16 = (const bf16_t*)Ap;
  const float*  a32 = (const float*)Ap;
  const bf16_t* b16 = (const bf16_t*)Bp;
  const float*  b32 = (const float*)Bp;

  bf16_t* lA0u = As + wave * 512;          // wave-uniform async bases
  bf16_t* lA1u = As + 2048 + wave * 512;
  bf16_t* lB0u = Bs + wave * 512;
  bf16_t* lB1u = Bs + 2048 + wave * 512;
  bf16_t* lA0p = lA0u + lane * 8;          // per-lane manual bases
  bf16_t* lA1p = lA1u + lane * 8;
  bf16_t* lB0p = lB0u + lane * 8;
  bf16_t* lB1p = lB1u + lane * 8;

  const int aoff = (wm + lc) * 32 + lq * 8;
  const int boff = (wn + lc) * 32 + lq * 8;

  for (int k = 0; k < K; k += 32) {
    if (a_f32) {
      stage32(a32 + (long)(m0 + srow) * lda + skoff + k, lA0p);
      stage32(a32 + (long)(m0 + srow + 64) * lda + skoff + k, lA1p);
    } else {
      ASYNC_COPY16(a16 + (long)(m0 + srow) * lda + skoff + k, lA0u);
      ASYNC_COPY16(a16 + (long)(m0 + srow + 64) * lda + skoff + k, lA1u);
    }
    if (b_f32) {
      stage32(b32 + (long)(n0 + srow) * ldb + skoff + k, lB0p);
      stage32(b32 + (long)(n0 + srow + 64) * ldb + skoff + k, lB1p);
    } else {
      ASYNC_COPY16(b16 + (long)(n0 + srow) * ldb + skoff + k, lB0u);
      ASYNC_COPY16(b16 + (long)(n0 + srow + 64) * ldb + skoff + k, lB1u);
    }
    __syncthreads();
    bf16x8 af[4], bfr[4];
#pragma unroll
    for (int i = 0; i < 4; ++i) {
      af[i]  = *reinterpret_cast<const bf16x8*>(&As[aoff + i * 512]);
      bfr[i] = *reinterpret_cast<const bf16x8*>(&Bs[boff + i * 512]);
    }
#pragma unroll
    for (int mi = 0; mi < 4; ++mi)
#pragma unroll
      for (int ni = 0; ni < 4; ++ni)
        acc[mi][ni] = mfma16x16(af[mi], bfr[ni], acc[mi][ni]);
    __syncthreads();
  }

  const bool c_f32 = CMODE && isf;
#pragma unroll
  for (int mi = 0; mi < 4; ++mi)
#pragma unroll
    for (int ni = 0; ni < 4; ++ni)
#pragma unroll
      for (int i = 0; i < 4; ++i) {
        const long row = m0 + wm + mi * 16 + lq * 4 + i;
        const long col = n0 + wn + ni * 16 + lc;
        const float v = acc[mi][ni][i];
        if (c_f32)
          ((float*)Cp)[row * ldc + col] = v;
        else
          ((bf16_t*)Cp)[row * ldc + col] = __float2bfloat16(v);
      }
}

// ---------------------------------------------------------------------------
// RoPE (neox half-split) in-place on Q and K regions of qkv (bf16).
// ---------------------------------------------------------------------------
__global__ void bh_rope(bf16_t* __restrict__ qkv, const int* __restrict__ pos) {
  const int idx = blockIdx.x * 256 + threadIdx.x;
  const int d = idx & 63;
  const int h = (idx >> 6) & (NH_ - 1);
  const int m = idx >> 11;
  if (m >= MTOK_) return;
  const float p = (float)pos[m];
  const float inv_freq = 1.0f / powf(10000.0f, (float)d * (1.0f / 64.0f));
  float sn, cs;
  sincosf(p * inv_freq, &sn, &cs);
  bf16_t* q  = qkv + (long)m * QKVN_ + h * HD_;
  bf16_t* kk = q + H_;
  const float q1 = __bfloat162float(q[d]);
  const float q2 = __bfloat162float(q[d + 64]);
  q[d]      = __float2bfloat16(q1 * cs - q2 * sn);
  q[d + 64] = __float2bfloat16(q2 * cs + q1 * sn);
  const float k1 = __bfloat162float(kk[d]);
  const float k2 = __bfloat162float(kk[d + 64]);
  kk[d]      = __float2bfloat16(k1 * cs - k2 * sn);
  kk[d + 64] = __float2bfloat16(k2 * cs + k1 * sn);
}

// ---------------------------------------------------------------------------
// V transpose: qkv V region [token][h*128+d] -> vt[b][h][d][token]
// ---------------------------------------------------------------------------
__global__ void bh_transpose_v(const bf16_t* __restrict__ qkv,
                               bf16_t* __restrict__ vt) {
  __shared__ unsigned short tile[128][65];
  const int t0 = blockIdx.x * 64;
  const int h  = blockIdx.y;
  const int b  = blockIdx.z;
  const int tid = threadIdx.x;
#pragma unroll
  for (int pass = 0; pass < 4; ++pass) {
    const int row = (tid >> 4) + pass * 16;
    const int dc  = (tid & 15) * 8;
    const u16x8 v = *reinterpret_cast<const u16x8*>(
        qkv + (long)(b * S_ + t0 + row) * QKVN_ + 2 * H_ + h * HD_ + dc);
#pragma unroll
    for (int j = 0; j < 8; ++j) tile[dc + j][row] = v[j];
  }
  __syncthreads();
#pragma unroll
  for (int pass = 0; pass < 4; ++pass) {
    const int d  = (tid >> 3) + pass * 32;
    const int tc = (tid & 7) * 8;
    u16x8 o;
#pragma unroll
    for (int j = 0; j < 8; ++j) o[j] = tile[d][tc + j];
    *reinterpret_cast<u16x8*>(
        vt + ((long)(b * NH_ + h) * HD_ + d) * S_ + t0 + tc) = o;
  }
}

// ---------------------------------------------------------------------------
// Causal flash attention. Output written into the Q region of qkv (each block
// overwrites exactly the Q rows/cols only it reads, after loading Q to regs).
//
// LDS tiles are XOR-swizzled (chunk ^= row&7 in 16B units) to kill the
// 16-way ds_read_b128 bank conflicts of the row-major layouts. Since
// global_load_lds writes linearly (lane i -> base + 16*i), the swizzle is
// applied on the per-lane GLOBAL source address (rule: both-sides-or-
// neither), and the identical XOR is applied on every ds_read.
// ---------------------------------------------------------------------------
__global__ __launch_bounds__(256)
void bh_flash(bf16_t* __restrict__ qkv, const bf16_t* __restrict__ vt) {
  __shared__ bf16_t Ks[64 * 128];   // [token][dim], dim-chunk ^= token&7
  __shared__ bf16_t Vs[128 * 64];   // [dim][token], token-chunk ^= dim&7
  __shared__ bf16_t Ps[128 * 64];   // [qrow][token], token-chunk ^= qrow&7
  const int qt = blockIdx.x, h = blockIdx.y, b = blockIdx.z;
  const int tid = threadIdx.x, wave = tid >> 6, lane = tid & 63;
  const int lq = lane >> 4, lc = lane & 15;
  const int wrow = wave * 32;
  const float scale = 0.088388347648318447f;  // 1/sqrt(128)

  bf16x8 qf[2][4];
#pragma unroll
  for (int mt = 0; mt < 2; ++mt) {
    const bf16_t* qp =
        qkv + (long)(b * S_ + qt * 128 + wrow + mt * 16 + lc) * QKVN_ +
        h * HD_ + lq * 8;
#pragma unroll
    for (int ks = 0; ks < 4; ++ks)
      qf[mt][ks] = *reinterpret_cast<const bf16x8*>(qp + ks * 32);
  }

  f32x4 o_acc[2][8] = {};
  float m_st[2][4], l_st[2][4];
#pragma unroll
  for (int mt = 0; mt < 2; ++mt)
#pragma unroll
    for (int i = 0; i < 4; ++i) { m_st[mt][i] = -1e30f; l_st[mt][i] = 0.f; }

  const int ktiles = 2 * qt + 2;
  for (int kt = 0; kt < ktiles; ++kt) {
    const int t0 = kt * 64;
#pragma unroll
    for (int j = 0; j < 4; ++j) {
      const int p = wave * 4 + j;
      // K: token trow, pre-swizzled dim-chunk so LDS ends up swizzled
      const int trow = p * 4 + (lane >> 4);
      const int kcs  = ((lane & 15) ^ (trow & 7)) * 8;
      ASYNC_COPY16(qkv + (long)(b * S_ + t0 + trow) * QKVN_ + H_ + h * HD_ + kcs,
                   Ks + p * 512);
      // V: dim vrow, pre-swizzled token-chunk
      const int vrow = p * 8 + (lane >> 3);
      const int tcs  = ((lane & 7) ^ (lane >> 3)) * 8;   // vrow&7 == lane>>3
      ASYNC_COPY16(vt + ((long)(b * NH_ + h) * HD_ + vrow) * S_ + t0 + tcs,
                   Vs + p * 512);
    }
    __syncthreads();

    f32x4 sa[2][4] = {};
#pragma unroll
    for (int ks = 0; ks < 4; ++ks) {
      bf16x8 bb[4];
#pragma unroll
      for (int nt = 0; nt < 4; ++nt)
        bb[nt] = *reinterpret_cast<const bf16x8*>(
            &Ks[(nt * 16 + lc) * 128 + ((ks * 32 + lq * 8) ^ ((lc & 7) << 3))]);
#pragma unroll
      for (int mt = 0; mt < 2; ++mt)
#pragma unroll
        for (int nt = 0; nt < 4; ++nt)
          sa[mt][nt] = mfma16x16(qf[mt][ks], bb[nt], sa[mt][nt]);
    }

#pragma unroll
    for (int mt = 0; mt < 2; ++mt) {
#pragma unroll
      for (int i = 0; i < 4; ++i) {
        const int qg = qt * 128 + wrow + mt * 16 + lq * 4 + i;
        float sv[4];
        float mloc = -1e30f;
#pragma unroll
        for (int nt = 0; nt < 4; ++nt) {
          float v = sa[mt][nt][i] * scale;
          if (t0 + nt * 16 + lc > qg) v = -1e30f;
          sv[nt] = v;
          mloc = fmaxf(mloc, v);
        }
#pragma unroll
        for (int off = 1; off < 16; off <<= 1)
          mloc = fmaxf(mloc, __shfl_xor(mloc, off, 64));
        const float mnew = fmaxf(m_st[mt][i], mloc);
        const float alpha = __expf(m_st[mt][i] - mnew);
        float rsum = 0.f;
        const int psw = ((lq * 4 + i) & 7) << 3;   // row&7 of the Ps row
#pragma unroll
        for (int nt = 0; nt < 4; ++nt) {
          const float pp = __expf(sv[nt] - mnew);
          rsum += pp;
          Ps[(wrow + mt * 16 + lq * 4 + i) * 64 + ((nt * 16 + lc) ^ psw)] =
              __float2bfloat16(pp);
        }
#pragma unroll
        for (int off = 1; off < 16; off <<= 1)
          rsum += __shfl_xor(rsum, off, 64);
        l_st[mt][i] = l_st[mt][i] * alpha + rsum;
        m_st[mt][i] = mnew;
#pragma unroll
        for (int nt = 0; nt < 8; ++nt) o_acc[mt][nt][i] *= alpha;
      }
    }
    __syncthreads();

#pragma unroll
    for (int ks = 0; ks < 2; ++ks) {
      bf16x8 pa[2];
#pragma unroll
      for (int mt = 0; mt < 2; ++mt)
        pa[mt] = *reinterpret_cast<const bf16x8*>(
            &Ps[(wrow + mt * 16 + lc) * 64 +
                ((ks * 32 + lq * 8) ^ ((lc & 7) << 3))]);
#pragma unroll
      for (int nt = 0; nt < 8; ++nt) {
        const bf16x8 vb = *reinterpret_cast<const bf16x8*>(
            &Vs[(nt * 16 + lc) * 64 +
                ((ks * 32 + lq * 8) ^ ((lc & 7) << 3))]);
#pragma unroll
        for (int mt = 0; mt < 2; ++mt)
          o_acc[mt][nt] = mfma16x16(pa[mt], vb, o_acc[mt][nt]);
      }
    }
    __syncthreads();
  }

  // write attention output into the Q region of qkv
#pragma unroll
  for (int mt = 0; mt < 2; ++mt)
#pragma unroll
    for (int i = 0; i < 4; ++i) {
      const float inv_l = 1.0f / l_st[mt][i];
      bf16_t* op =
          qkv + (long)(b * S_ + qt * 128 + wrow + mt * 16 + lq * 4 + i) * QKVN_ +
          h * HD_ + lc;
#pragma unroll
      for (int nt = 0; nt < 8; ++nt)
        op[nt * 16] = __float2bfloat16(o_acc[mt][nt][i] * inv_l);
    }
}

// ---------------------------------------------------------------------------
extern "C" void kernel_launch(void* const* d_in, const int* in_sizes, int n_in,
                              void* d_out, int out_size, void* d_ws,
                              size_t ws_size, hipStream_t stream) {
  const int* pos = (const int*)d_in[3];

  char* ws = (char*)d_ws;
  bf16_t* qkv  = (bf16_t*)ws;                                   // 100.66 MB
  const size_t QKV_B = (size_t)MTOK_ * QKVN_ * 2;
  int*    flag = (int*)(ws + QKV_B);
  bf16_t* vt   = (bf16_t*)d_out;  // scratch before final out is written

  // tiered bf16 conversion scratch (enables global_load_lds in the GEMMs)
  const size_t off  = QKV_B + 512;
  const size_t WP_B = (size_t)QKVN_ * H_ * 2;   // 100.66 MB
  const size_t WO_B = (size_t)H_ * H_ * 2;      //  33.55 MB
  const size_t A_B  = (size_t)MTOK_ * H_ * 2;   //  33.55 MB
  const bool cvtWP = ws_size >= off + WP_B;
  const bool cvtWO = ws_size >= off + WP_B + WO_B;
  const bool cvtA  = ws_size >= off + WP_B + WO_B + A_B;
  bf16_t* wpb = (bf16_t*)(ws + off);
  bf16_t* wob = (bf16_t*)(ws + off + WP_B);
  bf16_t* abf = (bf16_t*)(ws + off + WP_B + WO_B);

  bh_detect<<<dim3(1), dim3(256), 0, stream>>>(
      (const unsigned short*)d_in[1], flag);

  if (cvtWP)
    bh_convert<<<dim3(2048), dim3(256), 0, stream>>>(
        d_in[1], wpb, (long)QKVN_ * H_ / 8, flag);
  if (cvtWO)
    bh_convert<<<dim3(2048), dim3(256), 0, stream>>>(
        d_in[2], wob, (long)H_ * H_ / 8, flag);
  if (cvtA)
    bh_convert<<<dim3(2048), dim3(256), 0, stream>>>(
        d_in[0], abf, (long)MTOK_ * H_ / 8, flag);

  if (cvtA)
    bh_gemm<0, 0, 0><<<dim3(QKVN_ / 128, MTOK_ / 128), dim3(256), 0, stream>>>(
        abf, H_, wpb, H_, qkv, QKVN_, QKVN_, H_, flag);
  else if (cvtWP)
    bh_gemm<1, 0, 0><<<dim3(QKVN_ / 128, MTOK_ / 128), dim3(256), 0, stream>>>(
        d_in[0], H_, wpb, H_, qkv, QKVN_, QKVN_, H_, flag);
  else
    bh_gemm<1, 1, 0><<<dim3(QKVN_ / 128, MTOK_ / 128), dim3(256), 0, stream>>>(
        d_in[0], H_, d_in[1], H_, qkv, QKVN_, QKVN_, H_, flag);

  bh_rope<<<dim3((MTOK_ * NH_ * 64) / 256), dim3(256), 0, stream>>>(qkv, pos);
  bh_transpose_v<<<dim3(S_ / 64, NH_, B_), dim3(256), 0, stream>>>(qkv, vt);
  bh_flash<<<dim3(S_ / 128, NH_, B_), dim3(256), 0, stream>>>(qkv, vt);

  if (cvtWO)
    bh_gemm<0, 0, 1><<<dim3(H_ / 128, MTOK_ / 128), dim3(256), 0, stream>>>(
        qkv, QKVN_, wob, H_, d_out, H_, H_, H_, flag);
  else
    bh_gemm<0, 1, 1><<<dim3(H_ / 128, MTOK_ / 128), dim3(256), 0, stream>>>(
        qkv, QKVN_, d_in[2], H_, d_out, H_, H_, H_, flag);
}

// Round 2
// 1409.793 us; speedup vs baseline: 1.2733x; 1.0862x over previous
//
#include <hip/hip_runtime.h>
#include <hip/hip_bf16.h>
#include <math.h>

#define B_    2
#define S_    2048
#define H_    4096
#define NH_   32
#define HD_   128
#define MTOK_ (B_ * S_)     // 4096 tokens
#define QKVN_ (3 * H_)      // 12288

using bf16_t = __hip_bfloat16;
typedef __bf16 bf16x8 __attribute__((ext_vector_type(8)));
typedef unsigned short u16x8 __attribute__((ext_vector_type(8)));
typedef float f32x4 __attribute__((ext_vector_type(4)));

// async global->LDS, 16B per lane; LDS base must be wave-uniform
// (HW writes lane i at base + i*16B).
#define ASYNC_COPY16(g, l)                                                     \
  __builtin_amdgcn_global_load_lds(                                            \
      (__attribute__((address_space(1))) void*)(g),                            \
      (__attribute__((address_space(3))) void*)(l), 16, 0, 0)

static __device__ __forceinline__ f32x4 mfma16x16(bf16x8 a, bf16x8 b, f32x4 c) {
  return __builtin_amdgcn_mfma_f32_16x16x32_bf16(a, b, c, 0, 0, 0);
}

static __device__ __forceinline__ float bits_to_f(unsigned short v) {
  union { unsigned int u; float f; } cv;
  cv.u = ((unsigned int)v) << 16;
  return cv.f;
}

// ---------------------------------------------------------------------------
// dtype probe: if the float inputs are fp32, random mantissa halves decode to
// huge bf16 values; if genuine bf16 (|x|<~0.2 here), all 64K u16s stay small.
// ---------------------------------------------------------------------------
__global__ void bh_detect(const unsigned short* __restrict__ p,
                          int* __restrict__ flag) {
  __shared__ float red[4];
  float m = 0.f;
  const int tid = threadIdx.x;
  for (int i = tid; i < 65536; i += 256) {
    const float f = fabsf(bits_to_f(p[i]));
    m = fmaxf(m, f);  // fmaxf(m, NaN) == m
  }
  for (int off = 1; off < 64; off <<= 1) m = fmaxf(m, __shfl_xor(m, off, 64));
  if ((tid & 63) == 0) red[tid >> 6] = m;
  __syncthreads();
  if (tid == 0) {
    const float mm = fmaxf(fmaxf(red[0], red[1]), fmaxf(red[2], red[3]));
    *flag = (mm > 1.0f) ? 1 : 0;  // 1 => inputs/outputs are fp32
  }
}

// ---------------------------------------------------------------------------
// one-shot dtype normalization: fp32 -> bf16 convert (or bf16 copy), so the
// GEMMs can always use the global_load_lds (async 16B) staging path.
// ---------------------------------------------------------------------------
__global__ __launch_bounds__(256)
void bh_convert(const void* __restrict__ src, bf16_t* __restrict__ dst,
                long n8, const int* __restrict__ flag) {
  const int isf = *flag;
  const long stride = (long)gridDim.x * 256;
  long i = (long)blockIdx.x * 256 + threadIdx.x;
  if (isf) {
    const f32x4* s = (const f32x4*)src;
    for (; i < n8; i += stride) {
      const f32x4 f0 = s[2 * i];
      const f32x4 f1 = s[2 * i + 1];
      bf16x8 o;
      o[0] = (__bf16)f0[0]; o[1] = (__bf16)f0[1];
      o[2] = (__bf16)f0[2]; o[3] = (__bf16)f0[3];
      o[4] = (__bf16)f1[0]; o[5] = (__bf16)f1[1];
      o[6] = (__bf16)f1[2]; o[7] = (__bf16)f1[3];
      *reinterpret_cast<bf16x8*>(dst + i * 8) = o;
    }
  } else {
    const u16x8* s = (const u16x8*)src;
    for (; i < n8; i += stride)
      reinterpret_cast<u16x8*>(dst)[i] = s[i];
  }
}

// fp32 staging: read 8 floats, convert, one ds_write_b128 (same LDS layout
// the async path produces).
static __device__ __forceinline__ void stage32(const float* __restrict__ g,
                                               bf16_t* __restrict__ l) {
  const f32x4 f0 = *reinterpret_cast<const f32x4*>(g);
  const f32x4 f1 = *reinterpret_cast<const f32x4*>(g + 4);
  bf16x8 o;
  o[0] = (__bf16)f0[0]; o[1] = (__bf16)f0[1];
  o[2] = (__bf16)f0[2]; o[3] = (__bf16)f0[3];
  o[4] = (__bf16)f1[0]; o[5] = (__bf16)f1[1];
  o[6] = (__bf16)f1[2]; o[7] = (__bf16)f1[3];
  *reinterpret_cast<bf16x8*>(l) = o;
}

// ---------------------------------------------------------------------------
// Fallback NT GEMM (128x128 tile, 2-barrier loop) for when the workspace is
// too small to pre-convert operands. Unchanged from the verified version.
// ---------------------------------------------------------------------------
template <int AMODE, int BMODE, int CMODE>
__global__ __launch_bounds__(256, 2)
void bh_gemm(const void* __restrict__ Ap, int lda,
             const void* __restrict__ Bp, int ldb,
             void* __restrict__ Cp, int ldc, int N, int K,
             const int* __restrict__ flag) {
  __shared__ bf16_t As[128 * 32];
  __shared__ bf16_t Bs[128 * 32];
  const int isf = *flag;
  const bool a_f32 = AMODE && isf;
  const bool b_f32 = BMODE && isf;

  const int tid = threadIdx.x, wave = tid >> 6, lane = tid & 63;
  const int lq = lane >> 4, lc = lane & 15;
  const int m0 = blockIdx.y * 128, n0 = blockIdx.x * 128;
  const int wm = (wave >> 1) * 64, wn = (wave & 1) * 64;

  f32x4 acc[4][4] = {};

  const int srow  = wave * 16 + (lane >> 2);
  const int skoff = (lane & 3) * 8;

  const bf16_t* a16 = (const bf16_t*)Ap;
  const float*  a32 = (const float*)Ap;
  const bf16_t* b16 = (const bf16_t*)Bp;
  const float*  b32 = (const float*)Bp;

  bf16_t* lA0u = As + wave * 512;
  bf16_t* lA1u = As + 2048 + wave * 512;
  bf16_t* lB0u = Bs + wave * 512;
  bf16_t* lB1u = Bs + 2048 + wave * 512;
  bf16_t* lA0p = lA0u + lane * 8;
  bf16_t* lA1p = lA1u + lane * 8;
  bf16_t* lB0p = lB0u + lane * 8;
  bf16_t* lB1p = lB1u + lane * 8;

  const int aoff = (wm + lc) * 32 + lq * 8;
  const int boff = (wn + lc) * 32 + lq * 8;

  for (int k = 0; k < K; k += 32) {
    if (a_f32) {
      stage32(a32 + (long)(m0 + srow) * lda + skoff + k, lA0p);
      stage32(a32 + (long)(m0 + srow + 64) * lda + skoff + k, lA1p);
    } else {
      ASYNC_COPY16(a16 + (long)(m0 + srow) * lda + skoff + k, lA0u);
      ASYNC_COPY16(a16 + (long)(m0 + srow + 64) * lda + skoff + k, lA1u);
    }
    if (b_f32) {
      stage32(b32 + (long)(n0 + srow) * ldb + skoff + k, lB0p);
      stage32(b32 + (long)(n0 + srow + 64) * ldb + skoff + k, lB1p);
    } else {
      ASYNC_COPY16(b16 + (long)(n0 + srow) * ldb + skoff + k, lB0u);
      ASYNC_COPY16(b16 + (long)(n0 + srow + 64) * ldb + skoff + k, lB1u);
    }
    __syncthreads();
    bf16x8 af[4], bfr[4];
#pragma unroll
    for (int i = 0; i < 4; ++i) {
      af[i]  = *reinterpret_cast<const bf16x8*>(&As[aoff + i * 512]);
      bfr[i] = *reinterpret_cast<const bf16x8*>(&Bs[boff + i * 512]);
    }
#pragma unroll
    for (int mi = 0; mi < 4; ++mi)
#pragma unroll
      for (int ni = 0; ni < 4; ++ni)
        acc[mi][ni] = mfma16x16(af[mi], bfr[ni], acc[mi][ni]);
    __syncthreads();
  }

  const bool c_f32 = CMODE && isf;
#pragma unroll
  for (int mi = 0; mi < 4; ++mi)
#pragma unroll
    for (int ni = 0; ni < 4; ++ni)
#pragma unroll
      for (int i = 0; i < 4; ++i) {
        const long row = m0 + wm + mi * 16 + lq * 4 + i;
        const long col = n0 + wn + ni * 16 + lc;
        const float v = acc[mi][ni][i];
        if (c_f32)
          ((float*)Cp)[row * ldc + col] = v;
        else
          ((bf16_t*)Cp)[row * ldc + col] = __float2bfloat16(v);
      }
}

// ---------------------------------------------------------------------------
// 256x256 8-phase bf16 NT GEMM (m201-style). BK=64, 8 waves (2Mx4N), per-wave
// C = 128x64 as 8x4 16x16 frags. LDS = 2 dbuf x 2 half x [128][64] per
// operand = 128 KiB. Per K-tile, 4 phases; each phase: {ds_read one half-tile
// of frags | issue one half-tile prefetch (2x global_load_lds) | barrier |
// lgkmcnt(0) | setprio(1) 16 MFMA setprio(0) | barrier}. Counted vmcnt(6)
// once per K-tile (3 half-tiles stay in flight). LDS XOR-swizzle
// chunk ^= row&7 (16B units), applied on the pre-swizzled GLOBAL source
// (global_load_lds writes linearly) and on every ds_read.
//
// Stage schedule (tile T): p0 -> (T+1, A-half1); p1 -> (T+2, A-half0);
// p2 -> (T+2, B-half0); p3 -> (T+2, B-half1). Slot-free ledger: a slot for
// tile T+2 = buf[T&1], whose half was last read by tile T at p0 (A-h0, B-h0)
// or p1 (B-h1); (T+1,A-h1) slot last read by T-1 at its p2. All stage issues
// are >=1 barrier after the last read of their slot. Wait ledger: vmcnt(6)
// at T.p3 drains through (T+1,A-h1) [issued T.p0], leaving (T+2,*) = 6 loads
// in flight => tile T+1's four half-tiles complete before T+1.p0's ds_reads.
// ---------------------------------------------------------------------------
#define GBAR()                                                                 \
  do {                                                                         \
    __builtin_amdgcn_s_barrier();                                              \
    __builtin_amdgcn_sched_barrier(0);                                         \
  } while (0)

#define LGKM0()                                                                \
  do {                                                                         \
    asm volatile("s_waitcnt lgkmcnt(0)" ::: "memory");                         \
    __builtin_amdgcn_sched_barrier(0);                                         \
  } while (0)

template <int CMODE>
__global__ __launch_bounds__(512, 2)
void bh_gemm2(const bf16_t* __restrict__ Ap, int lda,
              const bf16_t* __restrict__ Bp, int ldb,
              void* __restrict__ Cp, int ldc, int K,
              const int* __restrict__ flag) {
  __shared__ bf16_t As[2][2][128 * 64];
  __shared__ bf16_t Bs[2][2][128 * 64];
  const int isf = *flag;

  const int tid = threadIdx.x, wave = tid >> 6, lane = tid & 63;
  const int lq = lane >> 4, lc = lane & 15;
  const int wm2 = wave >> 2;   // 0..1 -> row offset wm2*64 inside each A half
  const int wn4 = wave & 3;    // 0..3 -> col offset wn4*32 inside each B half
  const int m0 = blockIdx.y * 256, n0 = blockIdx.x * 256;
  const int NT = K >> 6;       // 64-wide K-tiles (NT >= 2 assumed)

  // staging geometry: wave w covers rows w*16..w*16+15 of a half-tile,
  // 2 issues of 8 rows (128B each). lane i -> row +(i>>3), chunk i&7;
  // global chunk pre-swizzled: gc = (i&7) ^ (i>>3)  (== chunk ^ (row&7)).
  const int srow = wave * 16 + (lane >> 3);
  const int gcol = ((lane & 7) ^ (lane >> 3)) * 8;
  const int lbase = wave * 1024;  // elements into a [128][64] half-tile

  f32x4 acc[8][4] = {};
  bf16x8 aA[2][4];      // current A half frags: [ks][f]
  bf16x8 bB[2][2][2];   // both B halves: [qn][ks][g]

  auto stageA = [&](int tau, int h) {
    if (tau >= NT) return;
    const bf16_t* g = Ap + (long)(m0 + h * 128 + srow) * lda + tau * 64 + gcol;
    bf16_t* l = &As[tau & 1][h][lbase];
    ASYNC_COPY16(g, l);
    ASYNC_COPY16(g + (long)8 * lda, l + 512);
  };
  auto stageB = [&](int tau, int h) {
    if (tau >= NT) return;
    const bf16_t* g = Bp + (long)(n0 + h * 128 + srow) * ldb + tau * 64 + gcol;
    bf16_t* l = &Bs[tau & 1][h][lbase];
    ASYNC_COPY16(g, l);
    ASYNC_COPY16(g + (long)8 * ldb, l + 512);
  };
  auto ldA = [&](int buf, int h) {
#pragma unroll
    for (int ks = 0; ks < 2; ++ks)
#pragma unroll
      for (int f = 0; f < 4; ++f) {
        const int row = wm2 * 64 + f * 16 + lc;
        aA[ks][f] = *reinterpret_cast<const bf16x8*>(
            &As[buf][h][row * 64 + (((ks * 4 + lq) ^ (row & 7)) * 8)]);
      }
  };
  auto ldB = [&](int buf, int h, bf16x8 (&dst)[2][2]) {
#pragma unroll
    for (int ks = 0; ks < 2; ++ks)
#pragma unroll
      for (int g = 0; g < 2; ++g) {
        const int row = wn4 * 32 + g * 16 + lc;
        dst[ks][g] = *reinterpret_cast<const bf16x8*>(
            &Bs[buf][h][row * 64 + (((ks * 4 + lq) ^ (row & 7)) * 8)]);
      }
  };

#define MMA_QUAD(qm, qn)                                                       \
  do {                                                                         \
    __builtin_amdgcn_s_setprio(1);                                             \
    _Pragma("unroll") for (int f = 0; f < 4; ++f) {                            \
      _Pragma("unroll") for (int g = 0; g < 2; ++g) {                          \
        f32x4 c = acc[(qm) * 4 + f][(qn) * 2 + g];                             \
        c = mfma16x16(aA[0][f], bB[qn][0][g], c);                              \
        c = mfma16x16(aA[1][f], bB[qn][1][g], c);                              \
        acc[(qm) * 4 + f][(qn) * 2 + g] = c;                                   \
      }                                                                        \
    }                                                                          \
    __builtin_amdgcn_s_setprio(0);                                             \
  } while (0)

  // prologue: tiles 0 (all 4 half-tiles) + tile 1 (A0,B0,B1), FIFO order
  // matching steady state; vmcnt(6) => tile0 complete, 3 half-tiles in flight.
  stageA(0, 0); stageB(0, 0); stageB(0, 1); stageA(0, 1);
  stageA(1, 0); stageB(1, 0); stageB(1, 1);
  asm volatile("s_waitcnt vmcnt(6)" ::: "memory");
  GBAR();

  for (int T = 0; T < NT; ++T) {
    const int buf = T & 1;
    // ---- phase 0: Q(0,0) = A-h0 x B-h0
    ldA(buf, 0);
    ldB(buf, 0, bB[0]);
    stageA(T + 1, 1);
    asm volatile("s_waitcnt lgkmcnt(8)" ::: "memory");
    GBAR();
    LGKM0();
    MMA_QUAD(0, 0);
    GBAR();
    // ---- phase 1: Q(0,1) = A-h0 x B-h1
    ldB(buf, 1, bB[1]);
    stageA(T + 2, 0);
    GBAR();
    LGKM0();
    MMA_QUAD(0, 1);
    GBAR();
    // ---- phase 2: Q(1,1) = A-h1 x B-h1
    ldA(buf, 1);
    stageB(T + 2, 0);
    GBAR();
    LGKM0();
    MMA_QUAD(1, 1);
    GBAR();
    // ---- phase 3: Q(1,0) = A-h1 x B-h0 (both already in regs)
    stageB(T + 2, 1);
    if (T + 2 < NT)
      asm volatile("s_waitcnt vmcnt(6)" ::: "memory");
    else
      asm volatile("s_waitcnt vmcnt(0)" ::: "memory");
    GBAR();
    MMA_QUAD(1, 0);
    GBAR();
  }

  const bool c_f32 = CMODE && isf;
#pragma unroll
  for (int mi = 0; mi < 8; ++mi)
#pragma unroll
    for (int ni = 0; ni < 4; ++ni)
#pragma unroll
      for (int i = 0; i < 4; ++i) {
        const long row =
            m0 + (mi >> 2) * 128 + wm2 * 64 + (mi & 3) * 16 + lq * 4 + i;
        const long col =
            n0 + (ni >> 1) * 128 + wn4 * 32 + (ni & 1) * 16 + lc;
        const float v = acc[mi][ni][i];
        if (c_f32)
          ((float*)Cp)[row * ldc + col] = v;
        else
          ((bf16_t*)Cp)[row * ldc + col] = __float2bfloat16(v);
      }
}

// ---------------------------------------------------------------------------
// RoPE (neox half-split) in-place on Q and K regions of qkv (bf16).
// ---------------------------------------------------------------------------
__global__ void bh_rope(bf16_t* __restrict__ qkv, const int* __restrict__ pos) {
  const int idx = blockIdx.x * 256 + threadIdx.x;
  const int d = idx & 63;
  const int h = (idx >> 6) & (NH_ - 1);
  const int m = idx >> 11;
  if (m >= MTOK_) return;
  const float p = (float)pos[m];
  const float inv_freq = 1.0f / powf(10000.0f, (float)d * (1.0f / 64.0f));
  float sn, cs;
  sincosf(p * inv_freq, &sn, &cs);
  bf16_t* q  = qkv + (long)m * QKVN_ + h * HD_;
  bf16_t* kk = q + H_;
  const float q1 = __bfloat162float(q[d]);
  const float q2 = __bfloat162float(q[d + 64]);
  q[d]      = __float2bfloat16(q1 * cs - q2 * sn);
  q[d + 64] = __float2bfloat16(q2 * cs + q1 * sn);
  const float k1 = __bfloat162float(kk[d]);
  const float k2 = __bfloat162float(kk[d + 64]);
  kk[d]      = __float2bfloat16(k1 * cs - k2 * sn);
  kk[d + 64] = __float2bfloat16(k2 * cs + k1 * sn);
}

// ---------------------------------------------------------------------------
// V transpose: qkv V region [token][h*128+d] -> vt[b][h][d][token]
// ---------------------------------------------------------------------------
__global__ void bh_transpose_v(const bf16_t* __restrict__ qkv,
                               bf16_t* __restrict__ vt) {
  __shared__ unsigned short tile[128][65];
  const int t0 = blockIdx.x * 64;
  const int h  = blockIdx.y;
  const int b  = blockIdx.z;
  const int tid = threadIdx.x;
#pragma unroll
  for (int pass = 0; pass < 4; ++pass) {
    const int row = (tid >> 4) + pass * 16;
    const int dc  = (tid & 15) * 8;
    const u16x8 v = *reinterpret_cast<const u16x8*>(
        qkv + (long)(b * S_ + t0 + row) * QKVN_ + 2 * H_ + h * HD_ + dc);
#pragma unroll
    for (int j = 0; j < 8; ++j) tile[dc + j][row] = v[j];
  }
  __syncthreads();
#pragma unroll
  for (int pass = 0; pass < 4; ++pass) {
    const int d  = (tid >> 3) + pass * 32;
    const int tc = (tid & 7) * 8;
    u16x8 o;
#pragma unroll
    for (int j = 0; j < 8; ++j) o[j] = tile[d][tc + j];
    *reinterpret_cast<u16x8*>(
        vt + ((long)(b * NH_ + h) * HD_ + d) * S_ + t0 + tc) = o;
  }
}

// ---------------------------------------------------------------------------
// Causal flash attention. Output written into the Q region of qkv (each block
// overwrites exactly the Q rows/cols only it reads, after loading Q to regs).
// LDS tiles XOR-swizzled (chunk ^= row&7, 16B units); swizzle applied on the
// global source for the async copies and on every ds_read.
// ---------------------------------------------------------------------------
__global__ __launch_bounds__(256)
void bh_flash(bf16_t* __restrict__ qkv, const bf16_t* __restrict__ vt) {
  __shared__ bf16_t Ks[64 * 128];   // [token][dim], dim-chunk ^= token&7
  __shared__ bf16_t Vs[128 * 64];   // [dim][token], token-chunk ^= dim&7
  __shared__ bf16_t Ps[128 * 64];   // [qrow][token], token-chunk ^= qrow&7
  const int qt = blockIdx.x, h = blockIdx.y, b = blockIdx.z;
  const int tid = threadIdx.x, wave = tid >> 6, lane = tid & 63;
  const int lq = lane >> 4, lc = lane & 15;
  const int wrow = wave * 32;
  const float scale = 0.088388347648318447f;  // 1/sqrt(128)

  bf16x8 qf[2][4];
#pragma unroll
  for (int mt = 0; mt < 2; ++mt) {
    const bf16_t* qp =
        qkv + (long)(b * S_ + qt * 128 + wrow + mt * 16 + lc) * QKVN_ +
        h * HD_ + lq * 8;
#pragma unroll
    for (int ks = 0; ks < 4; ++ks)
      qf[mt][ks] = *reinterpret_cast<const bf16x8*>(qp + ks * 32);
  }

  f32x4 o_acc[2][8] = {};
  float m_st[2][4], l_st[2][4];
#pragma unroll
  for (int mt = 0; mt < 2; ++mt)
#pragma unroll
    for (int i = 0; i < 4; ++i) { m_st[mt][i] = -1e30f; l_st[mt][i] = 0.f; }

  const int ktiles = 2 * qt + 2;
  for (int kt = 0; kt < ktiles; ++kt) {
    const int t0 = kt * 64;
#pragma unroll
    for (int j = 0; j < 4; ++j) {
      const int p = wave * 4 + j;
      const int trow = p * 4 + (lane >> 4);
      const int kcs  = ((lane & 15) ^ (trow & 7)) * 8;
      ASYNC_COPY16(qkv + (long)(b * S_ + t0 + trow) * QKVN_ + H_ + h * HD_ + kcs,
                   Ks + p * 512);
      const int vrow = p * 8 + (lane >> 3);
      const int tcs  = ((lane & 7) ^ (lane >> 3)) * 8;   // vrow&7 == lane>>3
      ASYNC_COPY16(vt + ((long)(b * NH_ + h) * HD_ + vrow) * S_ + t0 + tcs,
                   Vs + p * 512);
    }
    __syncthreads();

    f32x4 sa[2][4] = {};
#pragma unroll
    for (int ks = 0; ks < 4; ++ks) {
      bf16x8 bb[4];
#pragma unroll
      for (int nt = 0; nt < 4; ++nt)
        bb[nt] = *reinterpret_cast<const bf16x8*>(
            &Ks[(nt * 16 + lc) * 128 + ((ks * 32 + lq * 8) ^ ((lc & 7) << 3))]);
#pragma unroll
      for (int mt = 0; mt < 2; ++mt)
#pragma unroll
        for (int nt = 0; nt < 4; ++nt)
          sa[mt][nt] = mfma16x16(qf[mt][ks], bb[nt], sa[mt][nt]);
    }

#pragma unroll
    for (int mt = 0; mt < 2; ++mt) {
#pragma unroll
      for (int i = 0; i < 4; ++i) {
        const int qg = qt * 128 + wrow + mt * 16 + lq * 4 + i;
        float sv[4];
        float mloc = -1e30f;
#pragma unroll
        for (int nt = 0; nt < 4; ++nt) {
          float v = sa[mt][nt][i] * scale;
          if (t0 + nt * 16 + lc > qg) v = -1e30f;
          sv[nt] = v;
          mloc = fmaxf(mloc, v);
        }
#pragma unroll
        for (int off = 1; off < 16; off <<= 1)
          mloc = fmaxf(mloc, __shfl_xor(mloc, off, 64));
        const float mnew = fmaxf(m_st[mt][i], mloc);
        const float alpha = __expf(m_st[mt][i] - mnew);
        float rsum = 0.f;
        const int psw = ((lq * 4 + i) & 7) << 3;   // row&7 of the Ps row
#pragma unroll
        for (int nt = 0; nt < 4; ++nt) {
          const float pp = __expf(sv[nt] - mnew);
          rsum += pp;
          Ps[(wrow + mt * 16 + lq * 4 + i) * 64 + ((nt * 16 + lc) ^ psw)] =
              __float2bfloat16(pp);
        }
#pragma unroll
        for (int off = 1; off < 16; off <<= 1)
          rsum += __shfl_xor(rsum, off, 64);
        l_st[mt][i] = l_st[mt][i] * alpha + rsum;
        m_st[mt][i] = mnew;
#pragma unroll
        for (int nt = 0; nt < 8; ++nt) o_acc[mt][nt][i] *= alpha;
      }
    }
    __syncthreads();

#pragma unroll
    for (int ks = 0; ks < 2; ++ks) {
      bf16x8 pa[2];
#pragma unroll
      for (int mt = 0; mt < 2; ++mt)
        pa[mt] = *reinterpret_cast<const bf16x8*>(
            &Ps[(wrow + mt * 16 + lc) * 64 +
                ((ks * 32 + lq * 8) ^ ((lc & 7) << 3))]);
#pragma unroll
      for (int nt = 0; nt < 8; ++nt) {
        const bf16x8 vb = *reinterpret_cast<const bf16x8*>(
            &Vs[(nt * 16 + lc) * 64 +
                ((ks * 32 + lq * 8) ^ ((lc & 7) << 3))]);
#pragma unroll
        for (int mt = 0; mt < 2; ++mt)
          o_acc[mt][nt] = mfma16x16(pa[mt], vb, o_acc[mt][nt]);
      }
    }
    __syncthreads();
  }

  // write attention output into the Q region of qkv
#pragma unroll
  for (int mt = 0; mt < 2; ++mt)
#pragma unroll
    for (int i = 0; i < 4; ++i) {
      const float inv_l = 1.0f / l_st[mt][i];
      bf16_t* op =
          qkv + (long)(b * S_ + qt * 128 + wrow + mt * 16 + lq * 4 + i) * QKVN_ +
          h * HD_ + lc;
#pragma unroll
      for (int nt = 0; nt < 8; ++nt)
        op[nt * 16] = __float2bfloat16(o_acc[mt][nt][i] * inv_l);
    }
}

// ---------------------------------------------------------------------------
extern "C" void kernel_launch(void* const* d_in, const int* in_sizes, int n_in,
                              void* d_out, int out_size, void* d_ws,
                              size_t ws_size, hipStream_t stream) {
  const int* pos = (const int*)d_in[3];

  char* ws = (char*)d_ws;
  bf16_t* qkv  = (bf16_t*)ws;                                   // 100.66 MB
  const size_t QKV_B = (size_t)MTOK_ * QKVN_ * 2;
  int*    flag = (int*)(ws + QKV_B);
  bf16_t* vt   = (bf16_t*)d_out;  // scratch before final out is written

  // tiered bf16 conversion scratch (enables global_load_lds in the GEMMs)
  const size_t off  = QKV_B + 512;
  const size_t WP_B = (size_t)QKVN_ * H_ * 2;   // 100.66 MB
  const size_t WO_B = (size_t)H_ * H_ * 2;      //  33.55 MB
  const size_t A_B  = (size_t)MTOK_ * H_ * 2;   //  33.55 MB
  const bool cvtWP = ws_size >= off + WP_B;
  const bool cvtWO = ws_size >= off + WP_B + WO_B;
  const bool cvtA  = ws_size >= off + WP_B + WO_B + A_B;
  bf16_t* wpb = (bf16_t*)(ws + off);
  bf16_t* wob = (bf16_t*)(ws + off + WP_B);
  bf16_t* abf = (bf16_t*)(ws + off + WP_B + WO_B);

  bh_detect<<<dim3(1), dim3(256), 0, stream>>>(
      (const unsigned short*)d_in[1], flag);

  if (cvtWP)
    bh_convert<<<dim3(2048), dim3(256), 0, stream>>>(
        d_in[1], wpb, (long)QKVN_ * H_ / 8, flag);
  if (cvtWO)
    bh_convert<<<dim3(2048), dim3(256), 0, stream>>>(
        d_in[2], wob, (long)H_ * H_ / 8, flag);
  if (cvtA)
    bh_convert<<<dim3(2048), dim3(256), 0, stream>>>(
        d_in[0], abf, (long)MTOK_ * H_ / 8, flag);

  if (cvtA)
    bh_gemm2<0><<<dim3(QKVN_ / 256, MTOK_ / 256), dim3(512), 0, stream>>>(
        abf, H_, wpb, H_, qkv, QKVN_, H_, flag);
  else if (cvtWP)
    bh_gemm<1, 0, 0><<<dim3(QKVN_ / 128, MTOK_ / 128), dim3(256), 0, stream>>>(
        d_in[0], H_, wpb, H_, qkv, QKVN_, QKVN_, H_, flag);
  else
    bh_gemm<1, 1, 0><<<dim3(QKVN_ / 128, MTOK_ / 128), dim3(256), 0, stream>>>(
        d_in[0], H_, d_in[1], H_, qkv, QKVN_, QKVN_, H_, flag);

  bh_rope<<<dim3((MTOK_ * NH_ * 64) / 256), dim3(256), 0, stream>>>(qkv, pos);
  bh_transpose_v<<<dim3(S_ / 64, NH_, B_), dim3(256), 0, stream>>>(qkv, vt);
  bh_flash<<<dim3(S_ / 128, NH_, B_), dim3(256), 0, stream>>>(qkv, vt);

  if (cvtWO)
    bh_gemm2<1><<<dim3(H_ / 256, MTOK_ / 256), dim3(512), 0, stream>>>(
        qkv, QKVN_, wob, H_, d_out, H_, H_, flag);
  else
    bh_gemm<0, 1, 1><<<dim3(H_ / 128, MTOK_ / 128), dim3(256), 0, stream>>>(
        qkv, QKVN_, d_in[2], H_, d_out, H_, H_, H_, flag);
}

// Round 3
// 1165.670 us; speedup vs baseline: 1.5400x; 1.2094x over previous
//
#include <hip/hip_runtime.h>
#include <hip/hip_bf16.h>
#include <math.h>

#define B_    2
#define S_    2048
#define H_    4096
#define NH_   32
#define HD_   128
#define MTOK_ (B_ * S_)     // 4096 tokens
#define QKVN_ (3 * H_)      // 12288

using bf16_t = __hip_bfloat16;
typedef __bf16 bf16x8 __attribute__((ext_vector_type(8)));
typedef unsigned short u16x8 __attribute__((ext_vector_type(8)));
typedef float f32x4 __attribute__((ext_vector_type(4)));

// async global->LDS, 16B per lane; LDS base must be wave-uniform
// (HW writes lane i at base + i*16B).
#define ASYNC_COPY16(g, l)                                                     \
  __builtin_amdgcn_global_load_lds(                                            \
      (__attribute__((address_space(1))) void*)(g),                            \
      (__attribute__((address_space(3))) void*)(l), 16, 0, 0)

static __device__ __forceinline__ f32x4 mfma16x16(bf16x8 a, bf16x8 b, f32x4 c) {
  return __builtin_amdgcn_mfma_f32_16x16x32_bf16(a, b, c, 0, 0, 0);
}

static __device__ __forceinline__ float bits_to_f(unsigned short v) {
  union { unsigned int u; float f; } cv;
  cv.u = ((unsigned int)v) << 16;
  return cv.f;
}

#define GBAR()                                                                 \
  do {                                                                         \
    __builtin_amdgcn_s_barrier();                                              \
    __builtin_amdgcn_sched_barrier(0);                                         \
  } while (0)

#define LGKM0()                                                                \
  do {                                                                         \
    asm volatile("s_waitcnt lgkmcnt(0)" ::: "memory");                         \
    __builtin_amdgcn_sched_barrier(0);                                         \
  } while (0)

// ---------------------------------------------------------------------------
// dtype probe: if the float inputs are fp32, random mantissa halves decode to
// huge bf16 values; if genuine bf16 (|x|<~0.2 here), all 64K u16s stay small.
// ---------------------------------------------------------------------------
__global__ void bh_detect(const unsigned short* __restrict__ p,
                          int* __restrict__ flag) {
  __shared__ float red[4];
  float m = 0.f;
  const int tid = threadIdx.x;
  for (int i = tid; i < 65536; i += 256) {
    const float f = fabsf(bits_to_f(p[i]));
    m = fmaxf(m, f);  // fmaxf(m, NaN) == m
  }
  for (int off = 1; off < 64; off <<= 1) m = fmaxf(m, __shfl_xor(m, off, 64));
  if ((tid & 63) == 0) red[tid >> 6] = m;
  __syncthreads();
  if (tid == 0) {
    const float mm = fmaxf(fmaxf(red[0], red[1]), fmaxf(red[2], red[3]));
    *flag = (mm > 1.0f) ? 1 : 0;  // 1 => inputs/outputs are fp32
  }
}

// ---------------------------------------------------------------------------
// one-shot dtype normalization: fp32 -> bf16 convert (or bf16 copy), so the
// GEMMs can always use the global_load_lds (async 16B) staging path.
// ---------------------------------------------------------------------------
__global__ __launch_bounds__(256)
void bh_convert(const void* __restrict__ src, bf16_t* __restrict__ dst,
                long n8, const int* __restrict__ flag) {
  const int isf = *flag;
  const long stride = (long)gridDim.x * 256;
  long i = (long)blockIdx.x * 256 + threadIdx.x;
  if (isf) {
    const f32x4* s = (const f32x4*)src;
    for (; i < n8; i += stride) {
      const f32x4 f0 = s[2 * i];
      const f32x4 f1 = s[2 * i + 1];
      bf16x8 o;
      o[0] = (__bf16)f0[0]; o[1] = (__bf16)f0[1];
      o[2] = (__bf16)f0[2]; o[3] = (__bf16)f0[3];
      o[4] = (__bf16)f1[0]; o[5] = (__bf16)f1[1];
      o[6] = (__bf16)f1[2]; o[7] = (__bf16)f1[3];
      *reinterpret_cast<bf16x8*>(dst + i * 8) = o;
    }
  } else {
    const u16x8* s = (const u16x8*)src;
    for (; i < n8; i += stride)
      reinterpret_cast<u16x8*>(dst)[i] = s[i];
  }
}

// fp32 staging: read 8 floats, convert, one ds_write_b128 (same LDS layout
// the async path produces).
static __device__ __forceinline__ void stage32(const float* __restrict__ g,
                                               bf16_t* __restrict__ l) {
  const f32x4 f0 = *reinterpret_cast<const f32x4*>(g);
  const f32x4 f1 = *reinterpret_cast<const f32x4*>(g + 4);
  bf16x8 o;
  o[0] = (__bf16)f0[0]; o[1] = (__bf16)f0[1];
  o[2] = (__bf16)f0[2]; o[3] = (__bf16)f0[3];
  o[4] = (__bf16)f1[0]; o[5] = (__bf16)f1[1];
  o[6] = (__bf16)f1[2]; o[7] = (__bf16)f1[3];
  *reinterpret_cast<bf16x8*>(l) = o;
}

// ---------------------------------------------------------------------------
// Fallback NT GEMM (128x128 tile, 2-barrier loop) for when the workspace is
// too small to pre-convert operands. Unchanged from the verified version.
// ---------------------------------------------------------------------------
template <int AMODE, int BMODE, int CMODE>
__global__ __launch_bounds__(256, 2)
void bh_gemm(const void* __restrict__ Ap, int lda,
             const void* __restrict__ Bp, int ldb,
             void* __restrict__ Cp, int ldc, int N, int K,
             const int* __restrict__ flag) {
  __shared__ bf16_t As[128 * 32];
  __shared__ bf16_t Bs[128 * 32];
  const int isf = *flag;
  const bool a_f32 = AMODE && isf;
  const bool b_f32 = BMODE && isf;

  const int tid = threadIdx.x, wave = tid >> 6, lane = tid & 63;
  const int lq = lane >> 4, lc = lane & 15;
  const int m0 = blockIdx.y * 128, n0 = blockIdx.x * 128;
  const int wm = (wave >> 1) * 64, wn = (wave & 1) * 64;

  f32x4 acc[4][4] = {};

  const int srow  = wave * 16 + (lane >> 2);
  const int skoff = (lane & 3) * 8;

  const bf16_t* a16 = (const bf16_t*)Ap;
  const float*  a32 = (const float*)Ap;
  const bf16_t* b16 = (const bf16_t*)Bp;
  const float*  b32 = (const float*)Bp;

  bf16_t* lA0u = As + wave * 512;
  bf16_t* lA1u = As + 2048 + wave * 512;
  bf16_t* lB0u = Bs + wave * 512;
  bf16_t* lB1u = Bs + 2048 + wave * 512;
  bf16_t* lA0p = lA0u + lane * 8;
  bf16_t* lA1p = lA1u + lane * 8;
  bf16_t* lB0p = lB0u + lane * 8;
  bf16_t* lB1p = lB1u + lane * 8;

  const int aoff = (wm + lc) * 32 + lq * 8;
  const int boff = (wn + lc) * 32 + lq * 8;

  for (int k = 0; k < K; k += 32) {
    if (a_f32) {
      stage32(a32 + (long)(m0 + srow) * lda + skoff + k, lA0p);
      stage32(a32 + (long)(m0 + srow + 64) * lda + skoff + k, lA1p);
    } else {
      ASYNC_COPY16(a16 + (long)(m0 + srow) * lda + skoff + k, lA0u);
      ASYNC_COPY16(a16 + (long)(m0 + srow + 64) * lda + skoff + k, lA1u);
    }
    if (b_f32) {
      stage32(b32 + (long)(n0 + srow) * ldb + skoff + k, lB0p);
      stage32(b32 + (long)(n0 + srow + 64) * ldb + skoff + k, lB1p);
    } else {
      ASYNC_COPY16(b16 + (long)(n0 + srow) * ldb + skoff + k, lB0u);
      ASYNC_COPY16(b16 + (long)(n0 + srow + 64) * ldb + skoff + k, lB1u);
    }
    __syncthreads();
    bf16x8 af[4], bfr[4];
#pragma unroll
    for (int i = 0; i < 4; ++i) {
      af[i]  = *reinterpret_cast<const bf16x8*>(&As[aoff + i * 512]);
      bfr[i] = *reinterpret_cast<const bf16x8*>(&Bs[boff + i * 512]);
    }
#pragma unroll
    for (int mi = 0; mi < 4; ++mi)
#pragma unroll
      for (int ni = 0; ni < 4; ++ni)
        acc[mi][ni] = mfma16x16(af[mi], bfr[ni], acc[mi][ni]);
    __syncthreads();
  }

  const bool c_f32 = CMODE && isf;
#pragma unroll
  for (int mi = 0; mi < 4; ++mi)
#pragma unroll
    for (int ni = 0; ni < 4; ++ni)
#pragma unroll
      for (int i = 0; i < 4; ++i) {
        const long row = m0 + wm + mi * 16 + lq * 4 + i;
        const long col = n0 + wn + ni * 16 + lc;
        const float v = acc[mi][ni][i];
        if (c_f32)
          ((float*)Cp)[row * ldc + col] = v;
        else
          ((bf16_t*)Cp)[row * ldc + col] = __float2bfloat16(v);
      }
}

// ---------------------------------------------------------------------------
// 256x256 8-phase bf16 NT GEMM (m201-style). See R1 notes: BK=64, 8 waves,
// counted vmcnt(6), XOR-swizzle chunk^=row&7 via pre-swizzled global source.
// ---------------------------------------------------------------------------
template <int CMODE>
__global__ __launch_bounds__(512, 2)
void bh_gemm2(const bf16_t* __restrict__ Ap, int lda,
              const bf16_t* __restrict__ Bp, int ldb,
              void* __restrict__ Cp, int ldc, int K,
              const int* __restrict__ flag) {
  __shared__ bf16_t As[2][2][128 * 64];
  __shared__ bf16_t Bs[2][2][128 * 64];
  const int isf = *flag;

  const int tid = threadIdx.x, wave = tid >> 6, lane = tid & 63;
  const int lq = lane >> 4, lc = lane & 15;
  const int wm2 = wave >> 2;
  const int wn4 = wave & 3;
  const int m0 = blockIdx.y * 256, n0 = blockIdx.x * 256;
  const int NT = K >> 6;

  const int srow = wave * 16 + (lane >> 3);
  const int gcol = ((lane & 7) ^ (lane >> 3)) * 8;
  const int lbase = wave * 1024;

  f32x4 acc[8][4] = {};
  bf16x8 aA[2][4];
  bf16x8 bB[2][2][2];

  auto stageA = [&](int tau, int h) {
    if (tau >= NT) return;
    const bf16_t* g = Ap + (long)(m0 + h * 128 + srow) * lda + tau * 64 + gcol;
    bf16_t* l = &As[tau & 1][h][lbase];
    ASYNC_COPY16(g, l);
    ASYNC_COPY16(g + (long)8 * lda, l + 512);
  };
  auto stageB = [&](int tau, int h) {
    if (tau >= NT) return;
    const bf16_t* g = Bp + (long)(n0 + h * 128 + srow) * ldb + tau * 64 + gcol;
    bf16_t* l = &Bs[tau & 1][h][lbase];
    ASYNC_COPY16(g, l);
    ASYNC_COPY16(g + (long)8 * ldb, l + 512);
  };
  auto ldA = [&](int buf, int h) {
#pragma unroll
    for (int ks = 0; ks < 2; ++ks)
#pragma unroll
      for (int f = 0; f < 4; ++f) {
        const int row = wm2 * 64 + f * 16 + lc;
        aA[ks][f] = *reinterpret_cast<const bf16x8*>(
            &As[buf][h][row * 64 + (((ks * 4 + lq) ^ (row & 7)) * 8)]);
      }
  };
  auto ldB = [&](int buf, int h, bf16x8 (&dst)[2][2]) {
#pragma unroll
    for (int ks = 0; ks < 2; ++ks)
#pragma unroll
      for (int g = 0; g < 2; ++g) {
        const int row = wn4 * 32 + g * 16 + lc;
        dst[ks][g] = *reinterpret_cast<const bf16x8*>(
            &Bs[buf][h][row * 64 + (((ks * 4 + lq) ^ (row & 7)) * 8)]);
      }
  };

#define MMA_QUAD(qm, qn)                                                       \
  do {                                                                         \
    __builtin_amdgcn_s_setprio(1);                                             \
    _Pragma("unroll") for (int f = 0; f < 4; ++f) {                            \
      _Pragma("unroll") for (int g = 0; g < 2; ++g) {                          \
        f32x4 c = acc[(qm) * 4 + f][(qn) * 2 + g];                             \
        c = mfma16x16(aA[0][f], bB[qn][0][g], c);                              \
        c = mfma16x16(aA[1][f], bB[qn][1][g], c);                              \
        acc[(qm) * 4 + f][(qn) * 2 + g] = c;                                   \
      }                                                                        \
    }                                                                          \
    __builtin_amdgcn_s_setprio(0);                                             \
  } while (0)

  stageA(0, 0); stageB(0, 0); stageB(0, 1); stageA(0, 1);
  stageA(1, 0); stageB(1, 0); stageB(1, 1);
  asm volatile("s_waitcnt vmcnt(6)" ::: "memory");
  GBAR();

  for (int T = 0; T < NT; ++T) {
    const int buf = T & 1;
    ldA(buf, 0);
    ldB(buf, 0, bB[0]);
    stageA(T + 1, 1);
    asm volatile("s_waitcnt lgkmcnt(8)" ::: "memory");
    GBAR();
    LGKM0();
    MMA_QUAD(0, 0);
    GBAR();
    ldB(buf, 1, bB[1]);
    stageA(T + 2, 0);
    GBAR();
    LGKM0();
    MMA_QUAD(0, 1);
    GBAR();
    ldA(buf, 1);
    stageB(T + 2, 0);
    GBAR();
    LGKM0();
    MMA_QUAD(1, 1);
    GBAR();
    stageB(T + 2, 1);
    if (T + 2 < NT)
      asm volatile("s_waitcnt vmcnt(6)" ::: "memory");
    else
      asm volatile("s_waitcnt vmcnt(0)" ::: "memory");
    GBAR();
    MMA_QUAD(1, 0);
    GBAR();
  }

  const bool c_f32 = CMODE && isf;
#pragma unroll
  for (int mi = 0; mi < 8; ++mi)
#pragma unroll
    for (int ni = 0; ni < 4; ++ni)
#pragma unroll
      for (int i = 0; i < 4; ++i) {
        const long row =
            m0 + (mi >> 2) * 128 + wm2 * 64 + (mi & 3) * 16 + lq * 4 + i;
        const long col =
            n0 + (ni >> 1) * 128 + wn4 * 32 + (ni & 1) * 16 + lc;
        const float v = acc[mi][ni][i];
        if (c_f32)
          ((float*)Cp)[row * ldc + col] = v;
        else
          ((bf16_t*)Cp)[row * ldc + col] = __float2bfloat16(v);
      }
}

// ---------------------------------------------------------------------------
// RoPE (neox half-split) in-place on Q and K regions of qkv (bf16).
// ---------------------------------------------------------------------------
__global__ void bh_rope(bf16_t* __restrict__ qkv, const int* __restrict__ pos) {
  const int idx = blockIdx.x * 256 + threadIdx.x;
  const int d = idx & 63;
  const int h = (idx >> 6) & (NH_ - 1);
  const int m = idx >> 11;
  if (m >= MTOK_) return;
  const float p = (float)pos[m];
  const float inv_freq = 1.0f / powf(10000.0f, (float)d * (1.0f / 64.0f));
  float sn, cs;
  sincosf(p * inv_freq, &sn, &cs);
  bf16_t* q  = qkv + (long)m * QKVN_ + h * HD_;
  bf16_t* kk = q + H_;
  const float q1 = __bfloat162float(q[d]);
  const float q2 = __bfloat162float(q[d + 64]);
  q[d]      = __float2bfloat16(q1 * cs - q2 * sn);
  q[d + 64] = __float2bfloat16(q2 * cs + q1 * sn);
  const float k1 = __bfloat162float(kk[d]);
  const float k2 = __bfloat162float(kk[d + 64]);
  kk[d]      = __float2bfloat16(k1 * cs - k2 * sn);
  kk[d + 64] = __float2bfloat16(k2 * cs + k1 * sn);
}

// ---------------------------------------------------------------------------
// V transpose: qkv V region [token][h*128+d] -> vt[b][h][d][token]
// ---------------------------------------------------------------------------
__global__ void bh_transpose_v(const bf16_t* __restrict__ qkv,
                               bf16_t* __restrict__ vt) {
  __shared__ unsigned short tile[128][65];
  const int t0 = blockIdx.x * 64;
  const int h  = blockIdx.y;
  const int b  = blockIdx.z;
  const int tid = threadIdx.x;
#pragma unroll
  for (int pass = 0; pass < 4; ++pass) {
    const int row = (tid >> 4) + pass * 16;
    const int dc  = (tid & 15) * 8;
    const u16x8 v = *reinterpret_cast<const u16x8*>(
        qkv + (long)(b * S_ + t0 + row) * QKVN_ + 2 * H_ + h * HD_ + dc);
#pragma unroll
    for (int j = 0; j < 8; ++j) tile[dc + j][row] = v[j];
  }
  __syncthreads();
#pragma unroll
  for (int pass = 0; pass < 4; ++pass) {
    const int d  = (tid >> 3) + pass * 32;
    const int tc = (tid & 7) * 8;
    u16x8 o;
#pragma unroll
    for (int j = 0; j < 8; ++j) o[j] = tile[d][tc + j];
    *reinterpret_cast<u16x8*>(
        vt + ((long)(b * NH_ + h) * HD_ + d) * S_ + t0 + tc) = o;
  }
}

// ---------------------------------------------------------------------------
// Causal flash attention, double-buffered K/V with counted vmcnt (no
// __syncthreads in the K-loop: it would drain vmcnt(0) and put the full
// stage latency on the critical path every tile). Per tile:
//   stage(t+1,nxt) | vmcnt(8) | s_barrier | QK^T | softmax(Ps wave-private,
//   no barrier) | PV | s_barrier.
// End barrier orders this tile's LDS reads vs next tile's DMA writes into
// the opposite buffer (1-gap). Grid is 1D longest-first: blocks 0..63 are
// all qt=15 (32 K-tiles), so the critical-path blocks start at t=0.
// LDS tiles XOR-swizzled (chunk ^= row&7, 16B units), swizzle applied on the
// global source of the async copies and on every ds_read.
// ---------------------------------------------------------------------------
__global__ __launch_bounds__(256)
void bh_flash(bf16_t* __restrict__ qkv, const bf16_t* __restrict__ vt) {
  __shared__ bf16_t Ks[2][64 * 128];   // [token][dim], dim-chunk ^= token&7
  __shared__ bf16_t Vs[2][128 * 64];   // [dim][token], token-chunk ^= dim&7
  __shared__ bf16_t Ps[128 * 64];      // [qrow][token], token-chunk ^= qrow&7
  const int idx = blockIdx.x;
  const int qt = (S_ / 128 - 1) - (idx >> 6);  // longest-first
  const int bh = idx & 63;
  const int b  = bh >> 5;
  const int h  = bh & (NH_ - 1);
  const int tid = threadIdx.x, wave = tid >> 6, lane = tid & 63;
  const int lq = lane >> 4, lc = lane & 15;
  const int wrow = wave * 32;
  const float scale = 0.088388347648318447f;  // 1/sqrt(128)

  bf16x8 qf[2][4];
#pragma unroll
  for (int mt = 0; mt < 2; ++mt) {
    const bf16_t* qp =
        qkv + (long)(b * S_ + qt * 128 + wrow + mt * 16 + lc) * QKVN_ +
        h * HD_ + lq * 8;
#pragma unroll
    for (int ks = 0; ks < 4; ++ks)
      qf[mt][ks] = *reinterpret_cast<const bf16x8*>(qp + ks * 32);
  }

  f32x4 o_acc[2][8] = {};
  float m_st[2][4], l_st[2][4];
#pragma unroll
  for (int mt = 0; mt < 2; ++mt)
#pragma unroll
    for (int i = 0; i < 4; ++i) { m_st[mt][i] = -1e30f; l_st[mt][i] = 0.f; }

  // stage K/V tile kt into buffer bsel (8 async copies per wave)
  auto stage = [&](int kt, int bsel) {
    const int t0 = kt * 64;
#pragma unroll
    for (int j = 0; j < 4; ++j) {
      const int p = wave * 4 + j;
      const int trow = p * 4 + (lane >> 4);
      const int kcs  = ((lane & 15) ^ (trow & 7)) * 8;
      ASYNC_COPY16(qkv + (long)(b * S_ + t0 + trow) * QKVN_ + H_ + h * HD_ + kcs,
                   &Ks[bsel][p * 512]);
      const int vrow = p * 8 + (lane >> 3);
      const int tcs  = ((lane & 7) ^ (lane >> 3)) * 8;   // vrow&7 == lane>>3
      ASYNC_COPY16(vt + ((long)(b * NH_ + h) * HD_ + vrow) * S_ + t0 + tcs,
                   &Vs[bsel][p * 512]);
    }
  };

  const int ktiles = 2 * qt + 2;
  stage(0, 0);

  for (int kt = 0; kt < ktiles; ++kt) {
    const int cur = kt & 1;
    if (kt + 1 < ktiles) {
      stage(kt + 1, cur ^ 1);
      asm volatile("s_waitcnt vmcnt(8)" ::: "memory");
    } else {
      asm volatile("s_waitcnt vmcnt(0)" ::: "memory");
    }
    GBAR();

    const int t0 = kt * 64;
    f32x4 sa[2][4] = {};
    __builtin_amdgcn_s_setprio(1);
#pragma unroll
    for (int ks = 0; ks < 4; ++ks) {
      bf16x8 bb[4];
#pragma unroll
      for (int nt = 0; nt < 4; ++nt)
        bb[nt] = *reinterpret_cast<const bf16x8*>(
            &Ks[cur][(nt * 16 + lc) * 128 +
                     ((ks * 32 + lq * 8) ^ ((lc & 7) << 3))]);
#pragma unroll
      for (int mt = 0; mt < 2; ++mt)
#pragma unroll
        for (int nt = 0; nt < 4; ++nt)
          sa[mt][nt] = mfma16x16(qf[mt][ks], bb[nt], sa[mt][nt]);
    }
    __builtin_amdgcn_s_setprio(0);

#pragma unroll
    for (int mt = 0; mt < 2; ++mt) {
#pragma unroll
      for (int i = 0; i < 4; ++i) {
        const int qg = qt * 128 + wrow + mt * 16 + lq * 4 + i;
        float sv[4];
        float mloc = -1e30f;
#pragma unroll
        for (int nt = 0; nt < 4; ++nt) {
          float v = sa[mt][nt][i] * scale;
          if (t0 + nt * 16 + lc > qg) v = -1e30f;
          sv[nt] = v;
          mloc = fmaxf(mloc, v);
        }
#pragma unroll
        for (int off = 1; off < 16; off <<= 1)
          mloc = fmaxf(mloc, __shfl_xor(mloc, off, 64));
        const float mnew = fmaxf(m_st[mt][i], mloc);
        const float alpha = __expf(m_st[mt][i] - mnew);
        float rsum = 0.f;
        const int psw = ((lq * 4 + i) & 7) << 3;   // row&7 of the Ps row
#pragma unroll
        for (int nt = 0; nt < 4; ++nt) {
          const float pp = __expf(sv[nt] - mnew);
          rsum += pp;
          Ps[(wrow + mt * 16 + lq * 4 + i) * 64 + ((nt * 16 + lc) ^ psw)] =
              __float2bfloat16(pp);
        }
#pragma unroll
        for (int off = 1; off < 16; off <<= 1)
          rsum += __shfl_xor(rsum, off, 64);
        l_st[mt][i] = l_st[mt][i] * alpha + rsum;
        m_st[mt][i] = mnew;
#pragma unroll
        for (int nt = 0; nt < 8; ++nt) o_acc[mt][nt][i] *= alpha;
      }
    }
    // no barrier: Ps rows written/read by the same wave only

    __builtin_amdgcn_s_setprio(1);
#pragma unroll
    for (int ks = 0; ks < 2; ++ks) {
      bf16x8 pa[2];
#pragma unroll
      for (int mt = 0; mt < 2; ++mt)
        pa[mt] = *reinterpret_cast<const bf16x8*>(
            &Ps[(wrow + mt * 16 + lc) * 64 +
                ((ks * 32 + lq * 8) ^ ((lc & 7) << 3))]);
#pragma unroll
      for (int nt = 0; nt < 8; ++nt) {
        const bf16x8 vb = *reinterpret_cast<const bf16x8*>(
            &Vs[cur][(nt * 16 + lc) * 64 +
                     ((ks * 32 + lq * 8) ^ ((lc & 7) << 3))]);
#pragma unroll
        for (int mt = 0; mt < 2; ++mt)
          o_acc[mt][nt] = mfma16x16(pa[mt], vb, o_acc[mt][nt]);
      }
    }
    __builtin_amdgcn_s_setprio(0);
    GBAR();   // this tile's reads done before next tile's DMA into buf^1
  }

  // write attention output into the Q region of qkv
#pragma unroll
  for (int mt = 0; mt < 2; ++mt)
#pragma unroll
    for (int i = 0; i < 4; ++i) {
      const float inv_l = 1.0f / l_st[mt][i];
      bf16_t* op =
          qkv + (long)(b * S_ + qt * 128 + wrow + mt * 16 + lq * 4 + i) * QKVN_ +
          h * HD_ + lc;
#pragma unroll
      for (int nt = 0; nt < 8; ++nt)
        op[nt * 16] = __float2bfloat16(o_acc[mt][nt][i] * inv_l);
    }
}

// ---------------------------------------------------------------------------
extern "C" void kernel_launch(void* const* d_in, const int* in_sizes, int n_in,
                              void* d_out, int out_size, void* d_ws,
                              size_t ws_size, hipStream_t stream) {
  const int* pos = (const int*)d_in[3];

  char* ws = (char*)d_ws;
  bf16_t* qkv  = (bf16_t*)ws;                                   // 100.66 MB
  const size_t QKV_B = (size_t)MTOK_ * QKVN_ * 2;
  int*    flag = (int*)(ws + QKV_B);
  bf16_t* vt   = (bf16_t*)d_out;  // scratch before final out is written

  // tiered bf16 conversion scratch (enables global_load_lds in the GEMMs)
  const size_t off  = QKV_B + 512;
  const size_t WP_B = (size_t)QKVN_ * H_ * 2;   // 100.66 MB
  const size_t WO_B = (size_t)H_ * H_ * 2;      //  33.55 MB
  const size_t A_B  = (size_t)MTOK_ * H_ * 2;   //  33.55 MB
  const bool cvtWP = ws_size >= off + WP_B;
  const bool cvtWO = ws_size >= off + WP_B + WO_B;
  const bool cvtA  = ws_size >= off + WP_B + WO_B + A_B;
  bf16_t* wpb = (bf16_t*)(ws + off);
  bf16_t* wob = (bf16_t*)(ws + off + WP_B);
  bf16_t* abf = (bf16_t*)(ws + off + WP_B + WO_B);

  bh_detect<<<dim3(1), dim3(256), 0, stream>>>(
      (const unsigned short*)d_in[1], flag);

  if (cvtWP)
    bh_convert<<<dim3(2048), dim3(256), 0, stream>>>(
        d_in[1], wpb, (long)QKVN_ * H_ / 8, flag);
  if (cvtWO)
    bh_convert<<<dim3(2048), dim3(256), 0, stream>>>(
        d_in[2], wob, (long)H_ * H_ / 8, flag);
  if (cvtA)
    bh_convert<<<dim3(2048), dim3(256), 0, stream>>>(
        d_in[0], abf, (long)MTOK_ * H_ / 8, flag);

  if (cvtA)
    bh_gemm2<0><<<dim3(QKVN_ / 256, MTOK_ / 256), dim3(512), 0, stream>>>(
        abf, H_, wpb, H_, qkv, QKVN_, H_, flag);
  else if (cvtWP)
    bh_gemm<1, 0, 0><<<dim3(QKVN_ / 128, MTOK_ / 128), dim3(256), 0, stream>>>(
        d_in[0], H_, wpb, H_, qkv, QKVN_, QKVN_, H_, flag);
  else
    bh_gemm<1, 1, 0><<<dim3(QKVN_ / 128, MTOK_ / 128), dim3(256), 0, stream>>>(
        d_in[0], H_, d_in[1], H_, qkv, QKVN_, QKVN_, H_, flag);

  bh_rope<<<dim3((MTOK_ * NH_ * 64) / 256), dim3(256), 0, stream>>>(qkv, pos);
  bh_transpose_v<<<dim3(S_ / 64, NH_, B_), dim3(256), 0, stream>>>(qkv, vt);
  bh_flash<<<dim3((S_ / 128) * NH_ * B_), dim3(256), 0, stream>>>(qkv, vt);

  if (cvtWO)
    bh_gemm2<1><<<dim3(H_ / 256, MTOK_ / 256), dim3(512), 0, stream>>>(
        qkv, QKVN_, wob, H_, d_out, H_, H_, flag);
  else
    bh_gemm<0, 1, 1><<<dim3(H_ / 128, MTOK_ / 128), dim3(256), 0, stream>>>(
        qkv, QKVN_, d_in[2], H_, d_out, H_, H_, H_, flag);
}